// Round 5
// baseline (477.412 us; speedup 1.0000x reference)
//
#include <hip/hip_runtime.h>
#include <hip/hip_fp16.h>

// MLPLowRankPredictor: FastFood (B,H,P,G,H,S) low-rank weight perturbation + 3-layer MLP.
// SEQ=64 BATCH=32 -> N=2048 tokens. Z=128, X=32, H=128, Y=16.
// Blocks: wd0: 0..31 (4 rows x 32 cols), bd0: 32, wd1: 33..160, bd1: 161,
//         wd2: 162..177, bd2: 178 (first 16 elems).
//
// R5 theory: front-end (I-fetch) bound. R0-R4 invariant: ~4096 waves each running
// a 10-30KB straight-line execute-once body => ~40K cyc/wave of I$ cold-streaming,
// insensitive to VALU count / LDS layout / coalescing (all varied, duration flat).
// Fix: small looped hot code + more work per wave:
//  - j-loop per wave (J=2 for K1-wd and K2): ONE ff_block call site in a
//    '#pragma unroll 1' loop -> ~3KB hot body, I$-warm after iter 1; K2 waves
//    4096 -> 2048 (exactly 8/CU).
//  - 1-wave blocks, 18.9KB LDS (16KB fp16 perm + params + W row) -> 8 blocks/CU;
//    __launch_bounds__(64,2) -> 2 waves/SIMD resident.
//  - params staged to wave-private LDS per j (wave-synchronous, zero barriers);
//    z / h1 / bd0 re-read from L2 per iteration (coalesced [c][t] layouts).

#define ZD 128
#define XD 32
#define HD 128
#define YD 16
#define NTOK 2048

__device__ __forceinline__ float2 pk_add(float2 a, float2 b) {
  float2 d;
  asm("v_pk_add_f32 %0, %1, %2" : "=v"(d) : "v"(a), "v"(b));
  return d;
}
__device__ __forceinline__ float2 pk_sub(float2 a, float2 b) {
  float2 d;
  asm("v_pk_add_f32 %0, %1, %2 neg_lo:[0,1] neg_hi:[0,1]" : "=v"(d) : "v"(a), "v"(b));
  return d;
}

// In-register FWHT over 128 elems stored as w[m] = (v[2m], v[2m+1]).
__device__ __forceinline__ void fwht128p(float2 w[64]) {
#pragma unroll
  for (int m = 0; m < 64; m++) {
    float a = w[m].x, b = w[m].y;
    w[m].x = a + b; w[m].y = a - b;
  }
#pragma unroll
  for (int sig = 1; sig < 64; sig <<= 1) {
#pragma unroll
    for (int m = 0; m < 64; m++) {
      if ((m & sig) == 0) {
        float2 a = w[m], b = w[m + sig];
        w[m] = pk_add(a, b);
        w[m + sig] = pk_sub(a, b);
      }
    }
  }
}

// Per-wave LDS: fp16 perm buffer + staged params + staged W row. 18944 B/block
// -> 8 blocks/CU. All access is wave-private or wave-synchronous: NO barriers.
struct WaveLds {
  unsigned int perm[4096];           // 16 KB, dword m*64+lane = half2(v[2m],v[2m+1])
  float2 pB[64], pG[64], pS[64], pW[64];
  int2   pP[64];
};

__device__ __forceinline__ void stage_j(WaveLds* L, int lane, int j,
    const float* __restrict__ ffB, const float* __restrict__ ffG,
    const float* __restrict__ ffS, const int* __restrict__ ffP,
    const float* __restrict__ Wrow) {
  // lane l stages dwords 2l,2l+1 of each 128-dword array; later read by all
  // lanes as broadcast ds_read. Same-wave write->read: in-order DS + single PC.
  L->pB[lane] = ((const float2*)(ffB + (size_t)j * ZD))[lane];
  L->pG[lane] = ((const float2*)(ffG + (size_t)j * ZD))[lane];
  L->pS[lane] = ((const float2*)(ffS + (size_t)j * ZD))[lane];
  L->pP[lane] = ((const int2*)(ffP + (size_t)j * ZD))[lane];
  L->pW[lane] = ((const float2*)Wrow)[lane];
}

// w holds z on entry; exit w = S * FWHT( G * perm( FWHT( B * z ) ) ).
// perm round trip: lane-private LDS column (write m*64+lane, read [row][2*lane+bit]).
__device__ __forceinline__ void ff_block(float2 w[64], WaveLds* L, int lane) {
#pragma unroll
  for (int m = 0; m < 64; m++) { float2 b = L->pB[m]; w[m].x *= b.x; w[m].y *= b.y; }
  fwht128p(w);
#pragma unroll
  for (int m = 0; m < 64; m++) {
    __half2 h2v = __floats2half2_rn(w[m].x, w[m].y);
    L->perm[m * 64 + lane] = *(const unsigned int*)&h2v;
  }
  const __half* ph = (const __half*)L->perm;
#pragma unroll
  for (int m = 0; m < 64; m++) {
    int2 pp = L->pP[m];
    float2 g = L->pG[m];
    w[m].x = g.x * __half2float(ph[(pp.x >> 1) * 128 + 2 * lane + (pp.x & 1)]);
    w[m].y = g.y * __half2float(ph[(pp.y >> 1) * 128 + 2 * lane + (pp.y & 1)]);
  }
  fwht128p(w);
#pragma unroll
  for (int m = 0; m < 64; m++) { float2 s = L->pS[m]; w[m].x *= s.x; w[m].y *= s.y; }
}

// K0: transpose z and x into pair-interleaved [c2][t] layout (once, tiny).
__global__ __launch_bounds__(64) void k0_transpose(
    const float* __restrict__ z, const float* __restrict__ x,
    float2* __restrict__ zT2, float2* __restrict__ xT2) {
  const int t = blockIdx.x * 64 + threadIdx.x;
  const float4* z4 = (const float4*)(z + (size_t)t * ZD);
#pragma unroll
  for (int k = 0; k < 32; k++) {
    float4 f = z4[k];
    zT2[(size_t)(2 * k) * NTOK + t] = make_float2(f.x, f.y);
    zT2[(size_t)(2 * k + 1) * NTOK + t] = make_float2(f.z, f.w);
  }
  const float4* x4 = (const float4*)(x + (size_t)t * XD);
#pragma unroll
  for (int k = 0; k < 8; k++) {
    float4 f = x4[k];
    xT2[(size_t)(2 * k) * NTOK + t] = make_float2(f.x, f.y);
    xT2[(size_t)(2 * k + 1) * NTOK + t] = make_float2(f.z, f.w);
  }
}

// K1: grid (32, 18), 1 wave. y<16: wd0 blocks {2y, 2y+1}; y=16: {bd0, bd1};
// y=17: {bd2}. Looped body, one ff_block call site.
__global__ __launch_bounds__(64, 2) void k1_layer0(
    const float2* __restrict__ xT2, const float2* __restrict__ zT2,
    const float* __restrict__ W0, const float* __restrict__ b0,
    const float* __restrict__ ffB, const float* __restrict__ ffG,
    const float* __restrict__ ffS, const int* __restrict__ ffP,
    float2* __restrict__ h1T2, float2* __restrict__ bd0T2,
    float2* __restrict__ h2bT2, float* __restrict__ bd2v) {
  __shared__ WaveLds L;
  const int lane = threadIdx.x;
  const int tg = blockIdx.x;   // 0..31
  const int y  = blockIdx.y;   // 0..17
  const int t = tg * 64 + lane;
  const int njj = (y == 17) ? 1 : 2;

  float2 xx[16];
#pragma unroll
  for (int i2 = 0; i2 < 16; i2++) xx[i2] = xT2[(size_t)i2 * NTOK + t];

#pragma unroll 1
  for (int jj = 0; jj < njj; jj++) {
    int j, type;  // 0=wd0, 1=bd0, 2=bd1, 3=bd2
    if (y < 16)      { j = 2 * y + jj;        type = 0; }
    else if (y == 16){ j = jj ? 161 : 32;     type = jj ? 2 : 1; }
    else             { j = 178;               type = 3; }

    stage_j(&L, lane, j, ffB, ffG, ffS, ffP, W0 + (size_t)(type == 0 ? j : 0) * 128);

    float2 w[64];
#pragma unroll
    for (int m = 0; m < 64; m++) w[m] = zT2[(size_t)m * NTOK + t];
    ff_block(w, &L, lane);

    if (type == 0) {
      const int b = j;
      float o[4];
#pragma unroll
      for (int r = 0; r < 4; r++) {
        float aw = 0.f, ab = 0.f;
#pragma unroll
        for (int i2 = 0; i2 < 16; i2++) {
          float2 ww = w[r * 16 + i2];
          float2 W02 = L.pW[r * 16 + i2];        // broadcast ds_read
          aw += ww.x * xx[i2].x + ww.y * xx[i2].y;
          ab += W02.x * xx[i2].x + W02.y * xx[i2].y;
        }
        o[r] = ab + b0[4 * b + r] + aw * (1.0f / 128.0f);  // pre-relu, pre-bd0
      }
      h1T2[(size_t)(2 * b) * NTOK + t] = make_float2(o[0], o[1]);
      h1T2[(size_t)(2 * b + 1) * NTOK + t] = make_float2(o[2], o[3]);
    } else if (type == 1) {
#pragma unroll
      for (int m = 0; m < 64; m++)
        bd0T2[(size_t)m * NTOK + t] =
            make_float2(w[m].x * (1.0f / 128.0f), w[m].y * (1.0f / 128.0f));
    } else if (type == 2) {
#pragma unroll
      for (int m = 0; m < 64; m++)
        h2bT2[(size_t)m * NTOK + t] =
            make_float2(w[m].x * (1.0f / 128.0f), w[m].y * (1.0f / 128.0f));
    } else {
#pragma unroll
      for (int m = 0; m < 8; m++) {
        bd2v[(size_t)(2 * m) * NTOK + t]     = w[m].x * (1.0f / 128.0f);
        bd2v[(size_t)(2 * m + 1) * NTOK + t] = w[m].y * (1.0f / 128.0f);
      }
    }
  }
}

// K2: grid (32, 64), 1 wave, J=2 rows per wave. h1 = relu(h1T2 + bd0T2) fused.
__global__ __launch_bounds__(64, 2) void k2_layer1(
    const float2* __restrict__ zT2,
    const float* __restrict__ W1, const float* __restrict__ b1,
    const float* __restrict__ ffB, const float* __restrict__ ffG,
    const float* __restrict__ ffS, const int* __restrict__ ffP,
    const float2* __restrict__ h1T2, const float2* __restrict__ bd0T2,
    float* __restrict__ h2T) {
  __shared__ WaveLds L;
  const int lane = threadIdx.x;
  const int tg = blockIdx.x;   // 0..31
  const int jp = blockIdx.y;   // 0..63
  const int t = tg * 64 + lane;

#pragma unroll 1
  for (int jj = 0; jj < 2; jj++) {
    const int jr = 2 * jp + jj;   // 0..127
    stage_j(&L, lane, 33 + jr, ffB, ffG, ffS, ffP, W1 + (size_t)jr * 128);

    float2 w[64];
#pragma unroll
    for (int m = 0; m < 64; m++) w[m] = zT2[(size_t)m * NTOK + t];
    ff_block(w, &L, lane);

    float aw = 0.f, ab = 0.f;
#pragma unroll
    for (int c2 = 0; c2 < 64; c2++) {
      float2 a = h1T2[(size_t)c2 * NTOK + t];    // coalesced, L2-hot
      float2 d = bd0T2[(size_t)c2 * NTOK + t];   // coalesced, L2-hot
      float e0 = fmaxf(a.x + d.x, 0.f), e1 = fmaxf(a.y + d.y, 0.f);
      float2 W12 = L.pW[c2];                     // broadcast ds_read
      aw += w[c2].x * e0 + w[c2].y * e1;
      ab += W12.x * e0 + W12.y * e1;
    }
    h2T[(size_t)jr * NTOK + t] = ab + b1[jr] + aw * (1.0f / 128.0f);  // pre-relu
  }
}

// K3: grid (32, 16), 1 wave, one wd2 row per wave.
__global__ __launch_bounds__(64, 2) void k3_layer2(
    const float2* __restrict__ zT2,
    const float* __restrict__ W2, const float* __restrict__ b2,
    const float* __restrict__ ffB, const float* __restrict__ ffG,
    const float* __restrict__ ffS, const int* __restrict__ ffP,
    const float* __restrict__ h2T, const float2* __restrict__ h2bT2,
    const float* __restrict__ bd2v, float* __restrict__ out) {
  __shared__ WaveLds L;
  const int lane = threadIdx.x;
  const int tg = blockIdx.x;   // 0..31
  const int b  = blockIdx.y;   // 0..15
  const int t = tg * 64 + lane;

  stage_j(&L, lane, 162 + b, ffB, ffG, ffS, ffP, W2 + (size_t)b * 128);

  float2 w[64];
#pragma unroll
  for (int m = 0; m < 64; m++) w[m] = zT2[(size_t)m * NTOK + t];
  ff_block(w, &L, lane);

  float aw = 0.f, ab = 0.f;
#pragma unroll
  for (int c2 = 0; c2 < 64; c2++) {
    float p0 = h2T[(size_t)(2 * c2) * NTOK + t];
    float p1 = h2T[(size_t)(2 * c2 + 1) * NTOK + t];
    float2 q = h2bT2[(size_t)c2 * NTOK + t];
    float e0 = fmaxf(p0 + q.x, 0.f), e1 = fmaxf(p1 + q.y, 0.f);
    float2 W22 = L.pW[c2];                       // broadcast ds_read
    aw += w[c2].x * e0 + w[c2].y * e1;
    ab += W22.x * e0 + W22.y * e1;
  }
  out[(size_t)t * YD + b] = ab + b2[b] + aw * (1.0f / 128.0f) + bd2v[(size_t)b * NTOK + t];
}

extern "C" void kernel_launch(void* const* d_in, const int* in_sizes, int n_in,
                              void* d_out, int out_size, void* d_ws, size_t ws_size,
                              hipStream_t stream) {
  const float* x  = (const float*)d_in[0];
  const float* z  = (const float*)d_in[1];
  const float* W0 = (const float*)d_in[2];
  const float* b0 = (const float*)d_in[3];
  const float* W1 = (const float*)d_in[4];
  const float* b1 = (const float*)d_in[5];
  const float* W2 = (const float*)d_in[6];
  const float* b2 = (const float*)d_in[7];
  const float* fB = (const float*)d_in[8];
  const float* fG = (const float*)d_in[9];
  const float* fS = (const float*)d_in[10];
  const int*   fP = (const int*)d_in[11];
  float* out = (float*)d_out;

  float2* zT2   = (float2*)d_ws;             // [64][2048] float2 = 1 MB
  float2* xT2   = zT2 + (size_t)64 * NTOK;   // [16][2048] float2 = 256 KB
  float2* h1T2  = xT2 + (size_t)16 * NTOK;   // 1 MB (pre-relu, no bd0)
  float2* bd0T2 = h1T2 + (size_t)64 * NTOK;  // 1 MB
  float2* h2bT2 = bd0T2 + (size_t)64 * NTOK; // 1 MB (bd1, /128 applied)
  float*  h2T   = (float*)(h2bT2 + (size_t)64 * NTOK);  // [128][2048] = 1 MB
  float*  bd2v  = h2T + (size_t)HD * NTOK;   // [16][2048] = 128 KB

  k0_transpose<<<dim3(32), 64, 0, stream>>>(z, x, zT2, xT2);
  k1_layer0<<<dim3(32, 18), 64, 0, stream>>>(xT2, zT2, W0, b0, fB, fG, fS, fP,
                                             h1T2, bd0T2, h2bT2, bd2v);
  k2_layer1<<<dim3(32, 64), 64, 0, stream>>>(zT2, W1, b1, fB, fG, fS, fP,
                                             h1T2, bd0T2, h2T);
  k3_layer2<<<dim3(32, 16), 64, 0, stream>>>(zT2, W2, b2, fB, fG, fS, fP,
                                             h2T, h2bT2, bd2v, out);
}

// Round 6
// 126.200 us; speedup vs baseline: 3.7830x; 3.7830x over previous
//
#include <hip/hip_runtime.h>
#include <hip/hip_fp16.h>

// MLPLowRankPredictor — R6: MFMA rewrite.
// FastFood is linear in z: wd_j = M_j z_t with M_j = (1/128) S·H·G·Pgather·H·B (128x128).
// KM builds all 179 M_j (f16). GF does D_j = M_j x Z^T per (j, 128-token strip) with
// v_mfma_f32_16x16x32_f16 and FUSES each layer's contraction into the epilogue
// (in-lane partials + shfl_xor cross-group reduce), so no big Y intermediate.
// Bias blocks (32,161,178) stored as tiny f16 tiles. ws ~9.8 MB. f32 accum everywhere;
// only M and z quantized to f16 (~7e-4 rel on wd-part; prior 1.95e-3 absmax passed).

#define NTOK 2048
#define SLOT (128 * 2048)

typedef _Float16 f16x8 __attribute__((ext_vector_type(8)));
typedef float f32x4 __attribute__((ext_vector_type(4)));
typedef unsigned int u32;

__device__ __forceinline__ float2 pk_add(float2 a, float2 b) {
  float2 d;
  asm("v_pk_add_f32 %0, %1, %2" : "=v"(d) : "v"(a), "v"(b));
  return d;
}
__device__ __forceinline__ float2 pk_sub(float2 a, float2 b) {
  float2 d;
  asm("v_pk_add_f32 %0, %1, %2 neg_lo:[0,1] neg_hi:[0,1]" : "=v"(d) : "v"(a), "v"(b));
  return d;
}

// In-register FWHT over 128 elems stored as w[m] = (v[2m], v[2m+1]). (Proven R3-R5.)
__device__ __forceinline__ void fwht128p(float2 w[64]) {
#pragma unroll
  for (int m = 0; m < 64; m++) {
    float a = w[m].x, b = w[m].y;
    w[m].x = a + b; w[m].y = a - b;
  }
#pragma unroll
  for (int sig = 1; sig < 64; sig <<= 1) {
#pragma unroll
    for (int m = 0; m < 64; m++) {
      if ((m & sig) == 0) {
        float2 a = w[m], b = w[m + sig];
        w[m] = pk_add(a, b);
        w[m + sig] = pk_sub(a, b);
      }
    }
  }
}

// KX: x [2048][32] -> xT [32][2048] f32 (tiny, once).
__global__ __launch_bounds__(64) void kx(const float* __restrict__ x,
                                         float* __restrict__ xT) {
  const int t = blockIdx.x * 64 + threadIdx.x;
  const float4* x4 = (const float4*)(x + (size_t)t * 32);
#pragma unroll
  for (int k = 0; k < 8; k++) {
    float4 f = x4[k];
    xT[(size_t)(4 * k + 0) * NTOK + t] = f.x;
    xT[(size_t)(4 * k + 1) * NTOK + t] = f.y;
    xT[(size_t)(4 * k + 2) * NTOK + t] = f.z;
    xT[(size_t)(4 * k + 3) * NTOK + t] = f.w;
  }
}

// KM: build M_j [v][u] f16, one block (128 thr) per j. Thread c builds column c:
// col_c[k] = B[c]*G[k]*(-1)^popc(P[k]&c); FWHT over k; scale S[v]/128.
// Transposed through a 32KB LDS tile, swept out flat-coalesced.
__global__ __launch_bounds__(128) void km(
    const float* __restrict__ ffB, const float* __restrict__ ffG,
    const float* __restrict__ ffS, const int* __restrict__ ffP,
    _Float16* __restrict__ M) {
  __shared__ _Float16 T[128 * 128];
  __shared__ float sG[128], sS[128];
  __shared__ int sP[128];
  const int tid = threadIdx.x;
  const int j = blockIdx.x;
  sG[tid] = ffG[(size_t)j * 128 + tid];
  sS[tid] = ffS[(size_t)j * 128 + tid];
  sP[tid] = ffP[(size_t)j * 128 + tid];
  __syncthreads();
  const float Bc = ffB[(size_t)j * 128 + tid];
  float2 w[64];
#pragma unroll
  for (int m = 0; m < 64; m++) {
    int p0 = sP[2 * m], p1 = sP[2 * m + 1];
    float s0 = (__popc(p0 & tid) & 1) ? -Bc : Bc;
    float s1 = (__popc(p1 & tid) & 1) ? -Bc : Bc;
    w[m].x = sG[2 * m] * s0;
    w[m].y = sG[2 * m + 1] * s1;
  }
  fwht128p(w);
#pragma unroll
  for (int m = 0; m < 64; m++) {
    T[(2 * m) * 128 + tid] = (_Float16)(w[m].x * sS[2 * m] * 0.0078125f);
    T[(2 * m + 1) * 128 + tid] = (_Float16)(w[m].y * sS[2 * m + 1] * 0.0078125f);
  }
  __syncthreads();
  const u32* Ts = (const u32*)T;
  u32* Mo = (u32*)(M + (size_t)j * 16384);
#pragma unroll 4
  for (int i = 0; i < 64; i++) Mo[i * 128 + tid] = Ts[i * 128 + tid];
}

// GF: per (strip, j-group): D = M_j x Z^T for a 128-token strip, MFMA 16x16x32 f16.
// 256 thr = 4 waves; wave wv owns t-cols [wv*32, wv*32+32); 8 v-tiles x 2 t-tiles.
// MODE 0: layer0 fused -> h1[r][t] = relu(W0x + wd0x + b0 + bd0)
// MODE 1: layer1 fused -> h2[jr][t] = relu(W1h1 + wd1h1 + b1 + bd1)
// MODE 2: layer2 fused -> out[t][b] = W2h2 + wd2h2 + b2 + bd2
// MODE 3: store D as f16 tile (bias blocks 32/161/178)
template <int MODE, int JB>
__global__ __launch_bounds__(256, 2) void gf(
    const _Float16* __restrict__ M, const float* __restrict__ z,
    int j0, int js,
    const float* __restrict__ aux0,   // xT / h1 / h2
    const float* __restrict__ aux1,   // W0 / W1 / W2
    const float* __restrict__ aux2,   // b0 / b1 / b2
    const _Float16* __restrict__ auxY,// bias tile (bd0/bd1/bd2)
    float* __restrict__ outp,         // h1 / h2 / out
    _Float16* __restrict__ yout) {    // MODE3 dest
  __shared__ _Float16 Asm[128 * 136];
  __shared__ _Float16 Bsm[128 * 136];
  const int tid = threadIdx.x;
  const int lane = tid & 63, wv = tid >> 6;
  const int ln = lane & 15, g = lane >> 4;
  const int strip = blockIdx.x;

  // stage B = z strip [t][u], f32->f16, padded rows (136) to break bank conflicts
  {
    const float4* zg = (const float4*)z + (size_t)(strip * 128) * 32;
#pragma unroll
    for (int i = 0; i < 16; i++) {
      int F = i * 256 + tid;
      int t = F >> 5, q = F & 31;
      float4 f = zg[(size_t)t * 32 + q];
      __half2 hlo = __floats2half2_rn(f.x, f.y);
      __half2 hhi = __floats2half2_rn(f.z, f.w);
      uint2 u = make_uint2(*(u32*)&hlo, *(u32*)&hhi);
      *(uint2*)(&Bsm[t * 136 + q * 4]) = u;
    }
  }

#pragma unroll 1
  for (int jj = 0; jj < JB; jj++) {
    const int j = j0 + (blockIdx.y * JB + jj) * js;
    // stage A = M_j [v][u] f16 (already f16 in global)
    {
      const uint4* Mg = (const uint4*)(M + (size_t)j * 16384);
#pragma unroll
      for (int i = 0; i < 8; i++) {
        int F = i * 256 + tid;
        int v = F >> 4, c = F & 15;
        uint4 q4 = Mg[F];
        *(uint4*)(&Asm[v * 136 + c * 8]) = q4;
      }
    }
    __syncthreads();

    f32x4 acc[8][2];
#pragma unroll
    for (int vt = 0; vt < 8; vt++)
#pragma unroll
      for (int tt = 0; tt < 2; tt++) {
        f32x4 zf = {0.f, 0.f, 0.f, 0.f};
        acc[vt][tt] = zf;
      }

#pragma unroll
    for (int ks = 0; ks < 4; ks++) {
      f16x8 af[8], bf[2];
#pragma unroll
      for (int vt = 0; vt < 8; vt++)
        af[vt] = *(const f16x8*)(&Asm[(vt * 16 + ln) * 136 + ks * 32 + g * 8]);
#pragma unroll
      for (int tt = 0; tt < 2; tt++)
        bf[tt] = *(const f16x8*)(&Bsm[(wv * 32 + tt * 16 + ln) * 136 + ks * 32 + g * 8]);
#pragma unroll
      for (int vt = 0; vt < 8; vt++)
#pragma unroll
        for (int tt = 0; tt < 2; tt++)
          acc[vt][tt] = __builtin_amdgcn_mfma_f32_16x16x32_f16(af[vt], bf[tt],
                                                               acc[vt][tt], 0, 0, 0);
    }

    // D[v][t]: v = vt*16 + g*4 + r, t(tt) = strip*128 + wv*32 + tt*16 + ln  [m89 layout]
    const int tg0 = strip * 128 + wv * 32 + ln;

    if constexpr (MODE == 3) {
      _Float16* yd = yout + (size_t)blockIdx.y * SLOT;
#pragma unroll
      for (int vt = 0; vt < 8; vt++)
#pragma unroll
        for (int tt = 0; tt < 2; tt++)
#pragma unroll
          for (int r = 0; r < 4; r++)
            yd[(size_t)(vt * 16 + g * 4 + r) * NTOK + tg0 + tt * 16] =
                (_Float16)acc[vt][tt][r];
    } else if constexpr (MODE == 0) {
      // layer 0: rows 4j..4j+3, i = v&31; rho = v>>5 = vt>>1 (g-independent!)
      float pw[2][4] = {{0, 0, 0, 0}, {0, 0, 0, 0}};
      float pb[2][4] = {{0, 0, 0, 0}, {0, 0, 0, 0}};
#pragma unroll
      for (int vt = 0; vt < 8; vt++) {
        const int rho = vt >> 1;
#pragma unroll
        for (int r = 0; r < 4; r++) {
          int i = (vt & 1) * 16 + g * 4 + r;
          float w0v = aux1[(4 * j + rho) * 32 + i];
          float x0 = aux0[(size_t)i * NTOK + tg0];
          float x1 = aux0[(size_t)i * NTOK + tg0 + 16];
          pw[0][rho] += acc[vt][0][r] * x0; pb[0][rho] += w0v * x0;
          pw[1][rho] += acc[vt][1][r] * x1; pb[1][rho] += w0v * x1;
        }
      }
#pragma unroll
      for (int tt = 0; tt < 2; tt++)
#pragma unroll
        for (int rho = 0; rho < 4; rho++) {
          pw[tt][rho] += __shfl_xor(pw[tt][rho], 16);
          pw[tt][rho] += __shfl_xor(pw[tt][rho], 32);
          pb[tt][rho] += __shfl_xor(pb[tt][rho], 16);
          pb[tt][rho] += __shfl_xor(pb[tt][rho], 32);
        }
      if (g == 0) {
#pragma unroll
        for (int tt = 0; tt < 2; tt++)
#pragma unroll
          for (int rho = 0; rho < 4; rho++) {
            int rr = 4 * j + rho, tgs = tg0 + tt * 16;
            float bd = (float)auxY[(size_t)rr * NTOK + tgs];
            float val = pb[tt][rho] + pw[tt][rho] + aux2[rr] + bd;
            outp[(size_t)rr * NTOK + tgs] = fmaxf(val, 0.f);
          }
      }
    } else {
      // layer 1 / layer 2: full-v dot with aux0 (h1 or h2)
      const int row = (MODE == 1) ? (j - 33) : (j - 162);
      float pw0 = 0.f, pw1 = 0.f, pb0 = 0.f, pb1 = 0.f;
#pragma unroll
      for (int vt = 0; vt < 8; vt++)
#pragma unroll
        for (int r = 0; r < 4; r++) {
          int v = vt * 16 + g * 4 + r;
          float wv_ = aux1[row * 128 + v];
          float h0 = aux0[(size_t)v * NTOK + tg0];
          float h1v = aux0[(size_t)v * NTOK + tg0 + 16];
          pw0 += acc[vt][0][r] * h0; pb0 += wv_ * h0;
          pw1 += acc[vt][1][r] * h1v; pb1 += wv_ * h1v;
        }
      pw0 += __shfl_xor(pw0, 16); pw0 += __shfl_xor(pw0, 32);
      pw1 += __shfl_xor(pw1, 16); pw1 += __shfl_xor(pw1, 32);
      pb0 += __shfl_xor(pb0, 16); pb0 += __shfl_xor(pb0, 32);
      pb1 += __shfl_xor(pb1, 16); pb1 += __shfl_xor(pb1, 32);
      if (g == 0) {
        float bias = aux2[row];
        float bd0 = (float)auxY[(size_t)row * NTOK + tg0];
        float bd1 = (float)auxY[(size_t)row * NTOK + tg0 + 16];
        float v0 = pb0 + pw0 + bias + bd0;
        float v1 = pb1 + pw1 + bias + bd1;
        if constexpr (MODE == 1) {
          outp[(size_t)row * NTOK + tg0] = fmaxf(v0, 0.f);
          outp[(size_t)row * NTOK + tg0 + 16] = fmaxf(v1, 0.f);
        } else {
          outp[(size_t)tg0 * 16 + row] = v0;
          outp[(size_t)(tg0 + 16) * 16 + row] = v1;
        }
      }
    }
    __syncthreads();  // WAR: A-tile restaged next jj
  }
}

extern "C" void kernel_launch(void* const* d_in, const int* in_sizes, int n_in,
                              void* d_out, int out_size, void* d_ws, size_t ws_size,
                              hipStream_t stream) {
  const float* x  = (const float*)d_in[0];
  const float* z  = (const float*)d_in[1];
  const float* W0 = (const float*)d_in[2];
  const float* b0 = (const float*)d_in[3];
  const float* W1 = (const float*)d_in[4];
  const float* b1 = (const float*)d_in[5];
  const float* W2 = (const float*)d_in[6];
  const float* b2 = (const float*)d_in[7];
  const float* fB = (const float*)d_in[8];
  const float* fG = (const float*)d_in[9];
  const float* fS = (const float*)d_in[10];
  const int*   fP = (const int*)d_in[11];
  float* out = (float*)d_out;
  (void)ws_size;

  char* p = (char*)d_ws;
  _Float16* Mbuf  = (_Float16*)p; p += (size_t)179 * 16384 * 2;  // 5.86 MB
  _Float16* Ybias = (_Float16*)p; p += (size_t)3 * SLOT * 2;     // 1.57 MB
  float* xT = (float*)p;          p += (size_t)32 * NTOK * 4;    // 256 KB
  float* h1 = (float*)p;          p += (size_t)128 * NTOK * 4;   // 1 MB
  float* h2 = (float*)p;          p += (size_t)128 * NTOK * 4;   // 1 MB

  kx<<<dim3(32), 64, 0, stream>>>(x, xT);
  km<<<dim3(179), 128, 0, stream>>>(fB, fG, fS, fP, Mbuf);
  // bias blocks: j=32 (bd0), j=161 (bd1) via stride 129; j=178 (bd2)
  gf<3, 1><<<dim3(16, 2), 256, 0, stream>>>(Mbuf, z, 32, 129,
      nullptr, nullptr, nullptr, nullptr, nullptr, Ybias);
  gf<3, 1><<<dim3(16, 1), 256, 0, stream>>>(Mbuf, z, 178, 0,
      nullptr, nullptr, nullptr, nullptr, nullptr, Ybias + 2 * SLOT);
  // layer 0: j 0..31 -> h1
  gf<0, 2><<<dim3(16, 16), 256, 0, stream>>>(Mbuf, z, 0, 1,
      xT, W0, b0, Ybias, h1, nullptr);
  // layer 1: j 33..160 -> h2
  gf<1, 2><<<dim3(16, 64), 256, 0, stream>>>(Mbuf, z, 33, 1,
      h1, W1, b1, Ybias + SLOT, h2, nullptr);
  // layer 2: j 162..177 -> out
  gf<2, 2><<<dim3(16, 8), 256, 0, stream>>>(Mbuf, z, 162, 1,
      h2, W2, b2, Ybias + 2 * SLOT, out, nullptr);
}

// Round 7
// 126.147 us; speedup vs baseline: 3.7846x; 1.0004x over previous
//
#include <hip/hip_runtime.h>
#include <hip/hip_fp16.h>

// MLPLowRankPredictor — R7: MFMA structure from R6 (126 us), minus overhead.
// wd_j = M_j z_t, M_j = (1/128) S·H·G·Pgather·H·B built once in f16 (km).
// gf<MODE> computes D_j = M_j Z^T per (strip, j) with mfma_f32_16x16x32_f16 and
// fuses the layer contraction in the epilogue. R7 changes vs R6:
//  - 7 -> 4 launches: kx dropped (x read row-major directly); gf<3> bias
//    launches + Ybias dropped (bias rows computed in-epilogue as f32 VALU dots
//    of staged f16 M-rows against LDS z, folded into the shfl reduction).
//  - epilogue vectorized: h1/h2 in [t][v] layout -> float4 h-reads/writes;
//    W rows staged to LDS (broadcast ds_read_b128) instead of per-lane scalar
//    global re-reads (was 128 scalar loads/lane/jj).

#define NTOK 2048

typedef _Float16 f16x8 __attribute__((ext_vector_type(8)));
typedef _Float16 f16x4 __attribute__((ext_vector_type(4)));
typedef float f32x4 __attribute__((ext_vector_type(4)));
typedef unsigned int u32;

__device__ __forceinline__ float2 pk_add(float2 a, float2 b) {
  float2 d;
  asm("v_pk_add_f32 %0, %1, %2" : "=v"(d) : "v"(a), "v"(b));
  return d;
}
__device__ __forceinline__ float2 pk_sub(float2 a, float2 b) {
  float2 d;
  asm("v_pk_add_f32 %0, %1, %2 neg_lo:[0,1] neg_hi:[0,1]" : "=v"(d) : "v"(a), "v"(b));
  return d;
}

__device__ __forceinline__ void fwht128p(float2 w[64]) {
#pragma unroll
  for (int m = 0; m < 64; m++) {
    float a = w[m].x, b = w[m].y;
    w[m].x = a + b; w[m].y = a - b;
  }
#pragma unroll
  for (int sig = 1; sig < 64; sig <<= 1) {
#pragma unroll
    for (int m = 0; m < 64; m++) {
      if ((m & sig) == 0) {
        float2 a = w[m], b = w[m + sig];
        w[m] = pk_add(a, b);
        w[m + sig] = pk_sub(a, b);
      }
    }
  }
}

// KM: build M_j [v][u] f16, one 128-thr block per j (proven in R6).
__global__ __launch_bounds__(128) void km(
    const float* __restrict__ ffB, const float* __restrict__ ffG,
    const float* __restrict__ ffS, const int* __restrict__ ffP,
    _Float16* __restrict__ M) {
  __shared__ _Float16 T[128 * 128];
  __shared__ float sG[128], sS[128];
  __shared__ int sP[128];
  const int tid = threadIdx.x;
  const int j = blockIdx.x;
  sG[tid] = ffG[(size_t)j * 128 + tid];
  sS[tid] = ffS[(size_t)j * 128 + tid];
  sP[tid] = ffP[(size_t)j * 128 + tid];
  __syncthreads();
  const float Bc = ffB[(size_t)j * 128 + tid];
  float2 w[64];
#pragma unroll
  for (int m = 0; m < 64; m++) {
    int p0 = sP[2 * m], p1 = sP[2 * m + 1];
    float s0 = (__popc(p0 & tid) & 1) ? -Bc : Bc;
    float s1 = (__popc(p1 & tid) & 1) ? -Bc : Bc;
    w[m].x = sG[2 * m] * s0;
    w[m].y = sG[2 * m + 1] * s1;
  }
  fwht128p(w);
#pragma unroll
  for (int m = 0; m < 64; m++) {
    T[(2 * m) * 128 + tid] = (_Float16)(w[m].x * sS[2 * m] * 0.0078125f);
    T[(2 * m + 1) * 128 + tid] = (_Float16)(w[m].y * sS[2 * m + 1] * 0.0078125f);
  }
  __syncthreads();
  const u32* Ts = (const u32*)T;
  u32* Mo = (u32*)(M + (size_t)j * 16384);
#pragma unroll 4
  for (int i = 0; i < 64; i++) Mo[i * 128 + tid] = Ts[i * 128 + tid];
}

// GF: per (strip, j-pair): D = M_j x Z^T (128x128 per strip), fused epilogue.
// MODE 0: h1[t][4j+rho] = relu(W0 x + wd0 x + b0 + bd0)      (j 0..31,  bias j=32)
// MODE 1: h2[t][row]    = relu(W1 h1 + wd1 h1 + b1 + bd1)    (j 33..160, bias 161)
// MODE 2: out[t][row]   = W2 h2 + wd2 h2 + b2 + bd2          (j 162..177, bias 178)
template <int MODE, int JB>
__global__ __launch_bounds__(256, 2) void gf(
    const _Float16* __restrict__ M, const float* __restrict__ z,
    int j0, int jbias,
    const float* __restrict__ xin,   // MODE0: x [t][32]
    const float* __restrict__ hin,   // MODE1/2: h [t][128]
    const float* __restrict__ Wp, const float* __restrict__ bp,
    float* __restrict__ outp) {
  __shared__ _Float16 Asm[128 * 136];
  __shared__ _Float16 Bsm[128 * 136];
  __shared__ _Float16 pM[4 * 136];   // bias M-rows (f16)
  __shared__ float pW[128];          // W rows (f32)
  const int tid = threadIdx.x;
  const int lane = tid & 63, wv = tid >> 6;
  const int ln = lane & 15, g = lane >> 4;
  const int strip = blockIdx.x;
  const int tl0 = wv * 32 + ln;            // local token (tt=0)
  const int tg0 = strip * 128 + tl0;       // global token (tt=0)

  // stage B = z strip [t][u] f32->f16, padded rows (136)
  {
    const float4* zg = (const float4*)z + (size_t)(strip * 128) * 32;
#pragma unroll
    for (int i = 0; i < 16; i++) {
      int F = i * 256 + tid;
      int t = F >> 5, q = F & 31;
      float4 f = zg[(size_t)t * 32 + q];
      __half2 hlo = __floats2half2_rn(f.x, f.y);
      __half2 hhi = __floats2half2_rn(f.z, f.w);
      uint2 u = make_uint2(*(u32*)&hlo, *(u32*)&hhi);
      *(uint2*)(&Bsm[t * 136 + q * 4]) = u;
    }
  }

  // MODE0: per-lane x values (only 8 distinct per token), hoisted out of jj loop
  float4 xa[2][2];
  if constexpr (MODE == 0) {
#pragma unroll
    for (int tt = 0; tt < 2; tt++) {
      const float* xr = xin + (size_t)(tg0 + tt * 16) * 32;
      xa[tt][0] = *(const float4*)(xr + g * 4);
      xa[tt][1] = *(const float4*)(xr + 16 + g * 4);
    }
  }

#pragma unroll 1
  for (int jj = 0; jj < JB; jj++) {
    const int row = blockIdx.y * JB + jj;
    const int j = j0 + row;

    // stage A = M_j [v][u] f16
    {
      const uint4* Mg = (const uint4*)(M + (size_t)j * 16384);
#pragma unroll
      for (int i = 0; i < 8; i++) {
        int F = i * 256 + tid;
        int v = F >> 4, c = F & 15;
        *(uint4*)(&Asm[v * 136 + c * 8]) = Mg[F];
      }
    }
    // stage bias M-rows + W rows
    if constexpr (MODE == 0) {
      {  // rows 4j..4j+3 of M_jbias (4 x 64 u32)
        const u32* src = (const u32*)(M + (size_t)jbias * 16384 + (size_t)(4 * j) * 128);
        int rr = tid >> 6, uu = tid & 63;
        *(u32*)(&pM[rr * 136 + uu * 2]) = src[rr * 64 + uu];
      }
      if (tid < 128) pW[tid] = Wp[(size_t)(4 * j) * 32 + tid];  // W0 rows 4j..4j+3
    } else {
      if (tid < 64) {  // row 'row' of M_jbias
        const u32* src = (const u32*)(M + (size_t)jbias * 16384 + (size_t)row * 128);
        *(u32*)(&pM[tid * 2]) = src[tid];
      }
      if (tid < 128) pW[tid] = Wp[(size_t)row * 128 + tid];
    }
    __syncthreads();

    f32x4 acc[8][2];
#pragma unroll
    for (int vt = 0; vt < 8; vt++)
#pragma unroll
      for (int tt = 0; tt < 2; tt++) {
        f32x4 zf = {0.f, 0.f, 0.f, 0.f};
        acc[vt][tt] = zf;
      }
#pragma unroll
    for (int ks = 0; ks < 4; ks++) {
      f16x8 af[8], bf[2];
#pragma unroll
      for (int vt = 0; vt < 8; vt++)
        af[vt] = *(const f16x8*)(&Asm[(vt * 16 + ln) * 136 + ks * 32 + g * 8]);
#pragma unroll
      for (int tt = 0; tt < 2; tt++)
        bf[tt] = *(const f16x8*)(&Bsm[(wv * 32 + tt * 16 + ln) * 136 + ks * 32 + g * 8]);
#pragma unroll
      for (int vt = 0; vt < 8; vt++)
#pragma unroll
        for (int tt = 0; tt < 2; tt++)
          acc[vt][tt] = __builtin_amdgcn_mfma_f32_16x16x32_f16(af[vt], bf[tt],
                                                               acc[vt][tt], 0, 0, 0);
    }
    // D[v][t]: v = vt*16 + g*4 + r, t = tg0 + tt*16   [m89-verified layout]

    if constexpr (MODE == 0) {
      float pw[2][4] = {{0, 0, 0, 0}, {0, 0, 0, 0}};
      float pb[2][4] = {{0, 0, 0, 0}, {0, 0, 0, 0}};
#pragma unroll
      for (int vt = 0; vt < 8; vt++) {
        const int rho = vt >> 1;
        const float4 w4 = *(const float4*)&pW[rho * 32 + (vt & 1) * 16 + g * 4];  // broadcast
#pragma unroll
        for (int r = 0; r < 4; r++) {
          const float* xp0 = &xa[0][vt & 1].x;
          const float* xp1 = &xa[1][vt & 1].x;
          const float* wp4 = &w4.x;
          pw[0][rho] += acc[vt][0][r] * xp0[r];
          pw[1][rho] += acc[vt][1][r] * xp1[r];
          pb[0][rho] += wp4[r] * xp0[r];
          pb[1][rho] += wp4[r] * xp1[r];
        }
      }
      // bias rows: bd[rho][t] = sum_u M32[4j+rho][u] z[t][u], u-split by g
#pragma unroll
      for (int tt = 0; tt < 2; tt++) {
#pragma unroll
        for (int uu = 0; uu < 8; uu++) {
          int u0 = g * 32 + uu * 4;
          f16x4 zh = *(const f16x4*)(&Bsm[(tl0 + tt * 16) * 136 + u0]);
          float zf0 = (float)zh[0], zf1 = (float)zh[1], zf2 = (float)zh[2], zf3 = (float)zh[3];
#pragma unroll
          for (int rho = 0; rho < 4; rho++) {
            f16x4 mh = *(const f16x4*)(&pM[rho * 136 + u0]);  // broadcast
            pw[tt][rho] += (float)mh[0] * zf0 + (float)mh[1] * zf1 +
                           (float)mh[2] * zf2 + (float)mh[3] * zf3;
          }
        }
      }
#pragma unroll
      for (int tt = 0; tt < 2; tt++)
#pragma unroll
        for (int rho = 0; rho < 4; rho++) {
          pw[tt][rho] += __shfl_xor(pw[tt][rho], 16);
          pw[tt][rho] += __shfl_xor(pw[tt][rho], 32);
          pb[tt][rho] += __shfl_xor(pb[tt][rho], 16);
          pb[tt][rho] += __shfl_xor(pb[tt][rho], 32);
        }
      if (g == 0) {
#pragma unroll
        for (int tt = 0; tt < 2; tt++) {
          float4 o;
          float* op = &o.x;
#pragma unroll
          for (int rho = 0; rho < 4; rho++)
            op[rho] = fmaxf(pb[tt][rho] + pw[tt][rho] + bp[4 * j + rho], 0.f);
          *(float4*)(outp + (size_t)(tg0 + tt * 16) * 128 + 4 * j) = o;
        }
      }
    } else {
      float pw0 = 0.f, pw1 = 0.f, pb0 = 0.f, pb1 = 0.f;
#pragma unroll
      for (int vt = 0; vt < 8; vt++) {
        const int v0 = vt * 16 + g * 4;
        const float4 w4 = *(const float4*)&pW[v0];                              // broadcast
        const float4 h0 = *(const float4*)(hin + (size_t)tg0 * 128 + v0);       // coalesced-ish
        const float4 h1v = *(const float4*)(hin + (size_t)(tg0 + 16) * 128 + v0);
        const float* wp4 = &w4.x;
        const float* hp0 = &h0.x;
        const float* hp1 = &h1v.x;
#pragma unroll
        for (int r = 0; r < 4; r++) {
          pw0 += acc[vt][0][r] * hp0[r];
          pw1 += acc[vt][1][r] * hp1[r];
          pb0 += wp4[r] * hp0[r];
          pb1 += wp4[r] * hp1[r];
        }
      }
      // bias row dot, u-split by g
#pragma unroll
      for (int uu = 0; uu < 8; uu++) {
        int u0 = g * 32 + uu * 4;
        f16x4 mh = *(const f16x4*)(&pM[u0]);                       // broadcast
        f16x4 z0 = *(const f16x4*)(&Bsm[tl0 * 136 + u0]);
        f16x4 z1 = *(const f16x4*)(&Bsm[(tl0 + 16) * 136 + u0]);
#pragma unroll
        for (int e = 0; e < 4; e++) {
          pw0 += (float)mh[e] * (float)z0[e];
          pw1 += (float)mh[e] * (float)z1[e];
        }
      }
      pw0 += __shfl_xor(pw0, 16); pw0 += __shfl_xor(pw0, 32);
      pw1 += __shfl_xor(pw1, 16); pw1 += __shfl_xor(pw1, 32);
      pb0 += __shfl_xor(pb0, 16); pb0 += __shfl_xor(pb0, 32);
      pb1 += __shfl_xor(pb1, 16); pb1 += __shfl_xor(pb1, 32);
      if (g == 0) {
        float bias = bp[row];
        float v0 = pb0 + pw0 + bias;
        float v1 = pb1 + pw1 + bias;
        if constexpr (MODE == 1) {
          outp[(size_t)tg0 * 128 + row] = fmaxf(v0, 0.f);
          outp[(size_t)(tg0 + 16) * 128 + row] = fmaxf(v1, 0.f);
        } else {
          outp[(size_t)tg0 * 16 + row] = v0;
          outp[(size_t)(tg0 + 16) * 16 + row] = v1;
        }
      }
    }
    __syncthreads();  // WAR: Asm/pM/pW restaged next jj
  }
}

extern "C" void kernel_launch(void* const* d_in, const int* in_sizes, int n_in,
                              void* d_out, int out_size, void* d_ws, size_t ws_size,
                              hipStream_t stream) {
  const float* x  = (const float*)d_in[0];
  const float* z  = (const float*)d_in[1];
  const float* W0 = (const float*)d_in[2];
  const float* b0 = (const float*)d_in[3];
  const float* W1 = (const float*)d_in[4];
  const float* b1 = (const float*)d_in[5];
  const float* W2 = (const float*)d_in[6];
  const float* b2 = (const float*)d_in[7];
  const float* fB = (const float*)d_in[8];
  const float* fG = (const float*)d_in[9];
  const float* fS = (const float*)d_in[10];
  const int*   fP = (const int*)d_in[11];
  float* out = (float*)d_out;
  (void)ws_size;

  char* p = (char*)d_ws;
  _Float16* Mbuf = (_Float16*)p; p += (size_t)179 * 16384 * 2;  // 5.86 MB
  float* h1 = (float*)p;         p += (size_t)NTOK * 128 * 4;   // 1 MB [t][v]
  float* h2 = (float*)p;         p += (size_t)NTOK * 128 * 4;   // 1 MB [t][v]

  km<<<dim3(179), 128, 0, stream>>>(fB, fG, fS, fP, Mbuf);
  gf<0, 2><<<dim3(16, 16), 256, 0, stream>>>(Mbuf, z, 0, 32, x, nullptr, W0, b0, h1);
  gf<1, 2><<<dim3(16, 64), 256, 0, stream>>>(Mbuf, z, 33, 161, nullptr, h1, W1, b1, h2);
  gf<2, 2><<<dim3(16, 8), 256, 0, stream>>>(Mbuf, z, 162, 178, nullptr, h2, W2, b2, out);
}